// Round 2
// baseline (80.574 us; speedup 1.0000x reference)
//
#include <hip/hip_runtime.h>
#include <math.h>

#define IMG    512
#define IMG2   (IMG*IMG)
#define SPANS  10          // ceil(512 / 56) column spans per image row-strip
#define OUTW   56          // valid output columns per 64-lane wave
#define STRIPH 32          // output rows per strip
#define STRIPS 16          // 512 / 32
#define NBATCH 32
#define NWAVES (SPANS*STRIPS*NBATCH)   // 5120
#define NPIX   8388608.0f

__device__ __forceinline__ float shfld(float x, int d) { return __shfl_down(x, d, 64); }

__global__ __launch_bounds__(256)
void lncc_main(const float* __restrict__ Tm, const float* __restrict__ Im,
               float* __restrict__ partial)
{
    const int tid  = threadIdx.x;
    const int lane = tid & 63;
    int wid = (blockIdx.x << 2) | (tid >> 6);
    wid = __builtin_amdgcn_readfirstlane(wid);   // wave-uniform -> SGPR math

    const int span  = wid % SPANS;
    const int rem   = wid / SPANS;
    const int strip = rem & (STRIPS - 1);
    const int batch = rem >> 4;

    const int x0 = span * OUTW;
    const int y0 = strip * STRIPH;

    // lane's loaded column; clamp + multiplicative mask for x borders
    const int   gx  = x0 + lane - 4;
    const float xm  = ((unsigned)gx < IMG) ? 1.0f : 0.0f;
    const int   gxc = gx < 0 ? 0 : (gx > IMG - 1 ? IMG - 1 : gx);
    const bool  outok = (lane < OUTW) && (x0 + lane < IMG);

    const float* tb = Tm + (size_t)batch * IMG2;
    const float* ib = Im + (size_t)batch * IMG2;

    float tr_[9], ir_[9];                 // raw-value ring (static idx via unroll)
    float w0 = 0.f, w1 = 0.f, w2 = 0.f, w3 = 0.f, w4 = 0.f;
    float lsum = 0.f;

    // ---- prologue: fill vertical window rows y0-4 .. y0+3 ----
    #pragma unroll
    for (int j = 0; j < 8; ++j) {
        const int gy = y0 - 4 + j;        // wave-uniform -> scalar branch
        float t = 0.f, v = 0.f;
        if ((unsigned)gy < IMG) {
            const int off = gy * IMG + gxc;
            t = tb[off] * xm; v = ib[off] * xm;
        }
        w0 += t; w1 += v;
        w2 = fmaf(t, t, w2); w3 = fmaf(v, v, w3); w4 = fmaf(t, v, w4);
        tr_[j] = t; ir_[j] = v;
    }

    // ---- main: one output row per iteration ----
    #pragma unroll
    for (int r = 0; r < STRIPH; ++r) {
        const int gy = y0 + 4 + r;
        float t = 0.f, v = 0.f;
        if ((unsigned)gy < IMG) {
            const int off = gy * IMG + gxc;
            t = tb[off] * xm; v = ib[off] * xm;
        }
        w0 += t; w1 += v;
        w2 = fmaf(t, t, w2); w3 = fmaf(v, v, w3); w4 = fmaf(t, v, w4);
        tr_[(r + 8) % 9] = t; ir_[(r + 8) % 9] = v;

        // horizontal 9-window: S2, S4, S8 tree + raw[+8]
        float a0 = w0 + shfld(w0, 1), a1 = w1 + shfld(w1, 1), a2 = w2 + shfld(w2, 1),
              a3 = w3 + shfld(w3, 1), a4 = w4 + shfld(w4, 1);
        a0 += shfld(a0, 2); a1 += shfld(a1, 2); a2 += shfld(a2, 2);
        a3 += shfld(a3, 2); a4 += shfld(a4, 2);
        a0 += shfld(a0, 4); a1 += shfld(a1, 4); a2 += shfld(a2, 4);
        a3 += shfld(a3, 4); a4 += shfld(a4, 4);
        const float W0 = a0 + shfld(w0, 8), W1 = a1 + shfld(w1, 8),
                    W2 = a2 + shfld(w2, 8), W3 = a3 + shfld(w3, 8),
                    W4 = a4 + shfld(w4, 8);

        // collapsed score: cross = W4 - W0*W1/81, Iv = W2 - W0^2/81, Jv = W3 - W1^2/81
        const float inv81 = 1.0f / 81.0f;
        const float cross = fmaf(-W0 * inv81, W1, W4);
        const float Iv    = fmaf(-W0 * inv81, W0, W2);
        const float Jv    = fmaf(-W1 * inv81, W1, W3);
        const float den   = fmaf(Iv, Jv, 1e-12f);
        const float sc    = cross * __builtin_amdgcn_rsqf(den);
        lsum += outok ? sc : 0.0f;

        // slide: drop oldest row (index r, slot r%9)
        const float to = tr_[r % 9], io = ir_[r % 9];
        w0 -= to; w1 -= io;
        w2 = fmaf(-to, to, w2); w3 = fmaf(-io, io, w3); w4 = fmaf(-to, io, w4);
    }

    // per-wave reduction, one global write (no block barrier needed)
    #pragma unroll
    for (int d = 32; d >= 1; d >>= 1) lsum += shfld(lsum, d);
    if (lane == 0) partial[wid] = lsum;
}

__global__ __launch_bounds__(256)
void lncc_reduce(const float* __restrict__ partial, float* __restrict__ out)
{
    __shared__ float ws[4];
    const int tid = threadIdx.x;
    float s = 0.f;
    #pragma unroll
    for (int i = 0; i < NWAVES / 256; ++i) s += partial[tid + i * 256];
    #pragma unroll
    for (int d = 32; d >= 1; d >>= 1) s += __shfl_down(s, d, 64);
    if ((tid & 63) == 0) ws[tid >> 6] = s;
    __syncthreads();
    if (tid == 0) out[0] = 1.0f - (ws[0] + ws[1] + ws[2] + ws[3]) / NPIX;
}

extern "C" void kernel_launch(void* const* d_in, const int* in_sizes, int n_in,
                              void* d_out, int out_size, void* d_ws, size_t ws_size,
                              hipStream_t stream)
{
    (void)in_sizes; (void)n_in; (void)out_size; (void)ws_size;
    const float* Tm = (const float*)d_in[0];   // template
    const float* Im = (const float*)d_in[1];   // image
    float* out  = (float*)d_out;
    float* part = (float*)d_ws;                // NWAVES floats of scratch

    lncc_main<<<NWAVES / 4, 256, 0, stream>>>(Tm, Im, part);
    lncc_reduce<<<1, 256, 0, stream>>>(part, out);
}

// Round 3
// 28.622 us; speedup vs baseline: 2.8151x; 2.8151x over previous
//
#include <hip/hip_runtime.h>
#include <math.h>

#define IMG    512
#define IMG2   (IMG*IMG)
#define TC     64
#define TR     32
#define ECC    72              // TC + 8 extended columns
#define PITCH  33              // TR + 1 rows, transposed layout V[ec][row]
#define NBATCH 32
#define NBLOCKS ((IMG/TC)*(IMG/TR)*NBATCH)   // 8*16*32 = 4096
#define NPIX   8388608.0f

typedef float f2 __attribute__((ext_vector_type(2)));
typedef float f4 __attribute__((ext_vector_type(4)));

// RNE-rounded pack of two f32 -> 2x bf16 in one u32 (bit pattern in a float).
__device__ __forceinline__ float pk_bf16(float a, float b) {
    float r;
    asm("v_cvt_pk_bf16_f32 %0, %1, %2" : "=v"(r) : "v"(a), "v"(b));
    return r;
}

__global__ __launch_bounds__(256, 4)
void lncc_main(const float* __restrict__ Tm, const float* __restrict__ Im,
               float* __restrict__ partial)
{
    __shared__ f4 V[ECC * PITCH];       // 38,016 B: {w0, w1, bf16(w2,w3), bf16(w4,w4)}
    __shared__ float wsum[4];

    const int tid = threadIdx.x;
    const int x0 = blockIdx.x * TC;
    const int y0 = blockIdx.y * TR;
    const size_t base = (size_t)blockIdx.z * IMG2;
    const float* tb = Tm + base;
    const float* ib = Im + base;

    // ---- Pass 1: vertical sliding 9-sums; 2 strips x 72 ext columns ----
    if (tid < 2 * ECC) {
        const int ec    = tid % ECC;
        const int strip = tid / ECC;           // 0,1 -> out rows [0,16) / [16,32)
        const int r0    = strip * 16;
        const int gx    = x0 + ec - 4;
        const float xm  = ((unsigned)gx < IMG) ? 1.0f : 0.0f;
        const int gxc   = gx < 0 ? 0 : (gx > IMG - 1 ? IMG - 1 : gx);
        const int Y     = y0 + r0 - 4;

        f2 ring[9];                            // raw (t,v) ring, static idx via unroll
        f2 w01 = {0.f, 0.f}, w23 = {0.f, 0.f};
        float w4 = 0.f;

        #pragma unroll
        for (int j = 0; j < 24; ++j) {
            const int gy  = Y + j;
            const float m = ((unsigned)gy < IMG) ? xm : 0.0f;
            const int gyc = gy < 0 ? 0 : (gy > IMG - 1 ? IMG - 1 : gy);
            const int off = (gyc << 9) + gxc;
            f2 tv;
            tv.x = tb[off] * m;
            tv.y = ib[off] * m;
            w01 += tv;
            w23 += tv * tv;
            w4  = fmaf(tv.x, tv.y, w4);
            ring[j % 9] = tv;
            if (j >= 8) {
                const int k = j - 8;           // output row within strip
                f4 e;
                e.x = w01.x; e.y = w01.y;
                e.z = pk_bf16(w23.x, w23.y);
                e.w = pk_bf16(w4, w4);         // both halves = w4: lane-order immune
                V[ec * PITCH + r0 + k] = e;    // ds_write_b128, 2-way banks (free)
                const f2 o = ring[k % 9];
                w01 -= o;
                w23 -= o * o;
                w4  = fmaf(-o.x, o.y, w4);
            }
        }
    }
    __syncthreads();

    // ---- Pass 2: horizontal sliding 9-sums + score; 32 rows x 8 segs ----
    float lsum = 0.f;
    {
        const int row = tid & 31;
        const int cb  = (tid >> 5) * 8;        // first output col of segment
        f2 r01[9], r23[9];
        float r4[9];
        f2 W01 = {0.f, 0.f}, W23 = {0.f, 0.f};
        float W4 = 0.f;
        const float inv81 = 1.0f / 81.0f;

        #pragma unroll
        for (int k = 0; k < 16; ++k) {
            const f4 e = V[(cb + k) * PITCH + row];   // lane-contiguous: conflict-free
            const unsigned u23 = __float_as_uint(e.z);
            const unsigned u4  = __float_as_uint(e.w);
            f2 h01; h01.x = e.x; h01.y = e.y;
            f2 h23;
            h23.x = __uint_as_float(u23 << 16);
            h23.y = __uint_as_float(u23 & 0xffff0000u);
            const float h4 = __uint_as_float(u4 & 0xffff0000u);
            W01 += h01; W23 += h23; W4 += h4;
            const int ri = k % 9;
            r01[ri] = h01; r23[ri] = h23; r4[ri] = h4;
            if (k >= 8) {
                const float t0 = W01.x * inv81;
                const float t1 = W01.y * inv81;
                const float cross = fmaf(-t0, W01.y, W4);
                const float Iv    = fmaf(-t0, W01.x, W23.x);
                const float Jv    = fmaf(-t1, W01.y, W23.y);
                const float den   = fmaf(Iv, Jv, 1e-12f);
                lsum += cross * __builtin_amdgcn_rsqf(den);
                const int o = (k - 8) % 9;
                W01 -= r01[o]; W23 -= r23[o]; W4 -= r4[o];
            }
        }
    }

    // ---- deterministic block reduction ----
    #pragma unroll
    for (int d = 32; d >= 1; d >>= 1) lsum += __shfl_down(lsum, d, 64);
    if ((tid & 63) == 0) wsum[tid >> 6] = lsum;
    __syncthreads();
    if (tid == 0) {
        const int bid = (blockIdx.z * gridDim.y + blockIdx.y) * gridDim.x + blockIdx.x;
        partial[bid] = wsum[0] + wsum[1] + wsum[2] + wsum[3];
    }
}

__global__ __launch_bounds__(256)
void lncc_reduce(const float* __restrict__ partial, float* __restrict__ out)
{
    __shared__ float ws[4];
    const int tid = threadIdx.x;
    float s = 0.f;
    #pragma unroll
    for (int i = 0; i < NBLOCKS / 256; ++i) s += partial[tid + i * 256];
    #pragma unroll
    for (int d = 32; d >= 1; d >>= 1) s += __shfl_down(s, d, 64);
    if ((tid & 63) == 0) ws[tid >> 6] = s;
    __syncthreads();
    if (tid == 0) out[0] = 1.0f - (ws[0] + ws[1] + ws[2] + ws[3]) / NPIX;
}

extern "C" void kernel_launch(void* const* d_in, const int* in_sizes, int n_in,
                              void* d_out, int out_size, void* d_ws, size_t ws_size,
                              hipStream_t stream)
{
    (void)in_sizes; (void)n_in; (void)out_size; (void)ws_size;
    const float* Tm = (const float*)d_in[0];   // template
    const float* Im = (const float*)d_in[1];   // image
    float* out  = (float*)d_out;
    float* part = (float*)d_ws;                // NBLOCKS floats of scratch

    dim3 grid(IMG / TC, IMG / TR, NBATCH);     // (8, 16, 32)
    lncc_main<<<grid, 256, 0, stream>>>(Tm, Im, part);
    lncc_reduce<<<1, 256, 0, stream>>>(part, out);
}